// Round 1
// baseline (199.258 us; speedup 1.0000x reference)
//
#include <hip/hip_runtime.h>
#include <math.h>

// Problem shape (from setup_inputs): B=16, C=256, H=W=128, HW=16384.
// Pipeline:
//   K1 stats:   per (b,c) block -> mean, max, std(ddof=1) into ws u[B][C][3]
//   K2 median+gate: per batch block -> median of 768 stats, cubed deviation,
//               depthwise conv1d(k=3), BN eval, sigmoid -> ws g[B][C]
//   K3 scale:   out = x * g[b,c]  (elementwise, float4)

__global__ void stats_kernel(const float* __restrict__ x,
                             float* __restrict__ u, int HW) {
    const int bc  = blockIdx.x;
    const int tid = threadIdx.x;
    const float4* __restrict__ x4 =
        (const float4*)(x + (size_t)bc * (size_t)HW);
    const int n4 = HW >> 2;

    float s = 0.f, q = 0.f, mx = -INFINITY;
    for (int i = tid; i < n4; i += 256) {
        float4 v = x4[i];
        s += (v.x + v.y) + (v.z + v.w);
        q += (v.x * v.x + v.y * v.y) + (v.z * v.z + v.w * v.w);
        mx = fmaxf(mx, fmaxf(fmaxf(v.x, v.y), fmaxf(v.z, v.w)));
    }
    // wave64 butterfly reduce
    for (int off = 32; off > 0; off >>= 1) {
        s  += __shfl_down(s, off);
        q  += __shfl_down(q, off);
        mx  = fmaxf(mx, __shfl_down(mx, off));
    }
    __shared__ float ss[4], sq[4], sm[4];
    const int wid = tid >> 6, lane = tid & 63;
    if (lane == 0) { ss[wid] = s; sq[wid] = q; sm[wid] = mx; }
    __syncthreads();
    if (tid == 0) {
        float S = ss[0] + ss[1] + ss[2] + ss[3];
        float Q = sq[0] + sq[1] + sq[2] + sq[3];
        float M = fmaxf(fmaxf(sm[0], sm[1]), fmaxf(sm[2], sm[3]));
        float mean = S / (float)HW;
        float var  = (Q - S * mean) / (float)(HW - 1);  // unbiased (ddof=1)
        var = fmaxf(var, 0.f);
        float* up = u + (size_t)bc * 3;
        up[0] = mean;
        up[1] = M;
        up[2] = sqrtf(var);
    }
}

// One block per batch. NV = C*3 = 768 values; median = mean of order stats
// ranks 383 and 384 (0-indexed), exactly matching jnp.median for even n.
__global__ void median_gate_kernel(const float* __restrict__ u,
                                   const float* __restrict__ w,
                                   const float* __restrict__ gamma,
                                   const float* __restrict__ beta,
                                   const float* __restrict__ rmean,
                                   const float* __restrict__ rvar,
                                   float* __restrict__ g, int C) {
    const int b   = blockIdx.x;
    const int tid = threadIdx.x;
    const int NV  = C * 3;  // 768
    __shared__ float sv[768];
    __shared__ float m0, m1;

    const float* ub = u + (size_t)b * NV;
    for (int i = tid; i < NV; i += 256) sv[i] = ub[i];
    __syncthreads();

    const int r0 = (NV - 1) / 2;  // 383
    const int r1 = NV / 2;        // 384
    for (int j = tid; j < NV; j += 256) {
        float v = sv[j];
        int lt = 0, eq = 0;
        for (int i = 0; i < NV; ++i) {
            float o = sv[i];
            lt += (o < v);
            eq += (o == v);
        }
        // unique value owns each rank; ties write identical value (benign)
        if (lt <= r0 && r0 < lt + eq) m0 = v;
        if (lt <= r1 && r1 < lt + eq) m1 = v;
    }
    __syncthreads();

    const float med = 0.5f * (m0 + m1);
    if (tid < C) {
        const int c = tid;
        float z = 0.f;
        #pragma unroll
        for (int k = 0; k < 3; ++k) {
            float d = sv[c * 3 + k] - med;
            z += (d * d * d) * w[c * 3 + k];
        }
        z = (z - rmean[c]) * rsqrtf(rvar[c] + 1e-5f) * gamma[c] + beta[c];
        g[(size_t)b * C + c] = 1.f / (1.f + expf(-z));
    }
}

__global__ void scale_kernel(const float* __restrict__ x,
                             const float* __restrict__ g,
                             float* __restrict__ out, size_t n4,
                             int log2_elems_per_bc_4) {
    const float4* __restrict__ x4 = (const float4*)x;
    float4* __restrict__ o4 = (float4*)out;
    size_t stride = (size_t)gridDim.x * blockDim.x;
    for (size_t i = (size_t)blockIdx.x * blockDim.x + threadIdx.x;
         i < n4; i += stride) {
        float gv = g[i >> log2_elems_per_bc_4];
        float4 v = x4[i];
        v.x *= gv; v.y *= gv; v.z *= gv; v.w *= gv;
        o4[i] = v;
    }
}

extern "C" void kernel_launch(void* const* d_in, const int* in_sizes, int n_in,
                              void* d_out, int out_size, void* d_ws, size_t ws_size,
                              hipStream_t stream) {
    const float* x     = (const float*)d_in[0];
    const float* w     = (const float*)d_in[1];
    const float* gamma = (const float*)d_in[2];
    const float* beta  = (const float*)d_in[3];
    const float* rmean = (const float*)d_in[4];
    const float* rvar  = (const float*)d_in[5];
    float* out = (float*)d_out;

    const int C  = in_sizes[2];              // 256 (gamma)
    const int B  = 16;
    const int HW = in_sizes[0] / (B * C);    // 16384

    float* u = (float*)d_ws;                 // [B][C][3]
    float* g = u + (size_t)B * C * 3;        // [B][C]

    stats_kernel<<<B * C, 256, 0, stream>>>(x, u, HW);
    median_gate_kernel<<<B, 256, 0, stream>>>(u, w, gamma, beta, rmean, rvar, g, C);

    const size_t n4 = (size_t)B * C * HW / 4;
    // log2(HW/4): HW=16384 -> 4096 float4 per (b,c) -> shift 12
    int shift = 0;
    while ((1u << shift) < (unsigned)(HW / 4)) ++shift;
    scale_kernel<<<2048, 256, 0, stream>>>(x, g, out, n4, shift);
}

// Round 3
// 158.114 us; speedup vs baseline: 1.2602x; 1.2602x over previous
//
#include <hip/hip_runtime.h>
#include <math.h>

// Shape: B=16, C=256, H=W=128, HW=16384. x = 256 MiB fp32 (== L3 size).
// K1 stats:  per (b,c) block -> mean, max, std(ddof=1) into ws u[B][C][3]
//            (normal loads: deliberately leave x resident in L3)
// K2 median+gate: per batch -> median of 768 stats, cubed dev, dw-conv1d(3),
//            BN eval, sigmoid -> ws g[B][C]
// K3 scale:  one block per (b,c): out = x * g[bc]; non-temporal stores so the
//            out-stream doesn't evict x from L3 (pass-2 reads want L3 hits)

typedef float fvec4 __attribute__((ext_vector_type(4)));

__global__ void stats_kernel(const float* __restrict__ x,
                             float* __restrict__ u, int HW) {
    const int bc  = blockIdx.x;
    const int tid = threadIdx.x;
    const float4* __restrict__ x4 =
        (const float4*)(x + (size_t)bc * (size_t)HW);
    const int n4 = HW >> 2;

    // two independent accumulator sets -> shorter dep chains, more MLP
    float s0 = 0.f, q0 = 0.f, m0 = -INFINITY;
    float s1 = 0.f, q1 = 0.f, m1 = -INFINITY;
    #pragma unroll 4
    for (int i = tid; i < n4; i += 512) {
        float4 v = x4[i];
        s0 += (v.x + v.y) + (v.z + v.w);
        q0 += (v.x * v.x + v.y * v.y) + (v.z * v.z + v.w * v.w);
        m0 = fmaxf(m0, fmaxf(fmaxf(v.x, v.y), fmaxf(v.z, v.w)));
        int j = i + 256;
        if (j < n4) {
            float4 w = x4[j];
            s1 += (w.x + w.y) + (w.z + w.w);
            q1 += (w.x * w.x + w.y * w.y) + (w.z * w.z + w.w * w.w);
            m1 = fmaxf(m1, fmaxf(fmaxf(w.x, w.y), fmaxf(w.z, w.w)));
        }
    }
    float s = s0 + s1, q = q0 + q1, mx = fmaxf(m0, m1);

    for (int off = 32; off > 0; off >>= 1) {
        s  += __shfl_down(s, off);
        q  += __shfl_down(q, off);
        mx  = fmaxf(mx, __shfl_down(mx, off));
    }
    __shared__ float ss[4], sq[4], sm[4];
    const int wid = tid >> 6, lane = tid & 63;
    if (lane == 0) { ss[wid] = s; sq[wid] = q; sm[wid] = mx; }
    __syncthreads();
    if (tid == 0) {
        float S = ss[0] + ss[1] + ss[2] + ss[3];
        float Q = sq[0] + sq[1] + sq[2] + sq[3];
        float M = fmaxf(fmaxf(sm[0], sm[1]), fmaxf(sm[2], sm[3]));
        float mean = S / (float)HW;
        float var  = (Q - S * mean) / (float)(HW - 1);  // unbiased (ddof=1)
        var = fmaxf(var, 0.f);
        float* up = u + (size_t)bc * 3;
        up[0] = mean;
        up[1] = M;
        up[2] = sqrtf(var);
    }
}

// One block per batch. NV = C*3 = 768; median = mean of ranks 383,384.
__global__ void median_gate_kernel(const float* __restrict__ u,
                                   const float* __restrict__ w,
                                   const float* __restrict__ gamma,
                                   const float* __restrict__ beta,
                                   const float* __restrict__ rmean,
                                   const float* __restrict__ rvar,
                                   float* __restrict__ g, int C) {
    const int b   = blockIdx.x;
    const int tid = threadIdx.x;
    const int NV  = C * 3;  // 768
    __shared__ float sv[768];
    __shared__ float m0, m1;

    const float* ub = u + (size_t)b * NV;
    for (int i = tid; i < NV; i += 256) sv[i] = ub[i];
    __syncthreads();

    const int r0 = (NV - 1) / 2;  // 383
    const int r1 = NV / 2;        // 384
    for (int j = tid; j < NV; j += 256) {
        float v = sv[j];
        int lt = 0, eq = 0;
        for (int i = 0; i < NV; ++i) {
            float o = sv[i];
            lt += (o < v);
            eq += (o == v);
        }
        if (lt <= r0 && r0 < lt + eq) m0 = v;
        if (lt <= r1 && r1 < lt + eq) m1 = v;
    }
    __syncthreads();

    const float med = 0.5f * (m0 + m1);
    if (tid < C) {
        const int c = tid;
        float z = 0.f;
        #pragma unroll
        for (int k = 0; k < 3; ++k) {
            float d = sv[c * 3 + k] - med;
            z += (d * d * d) * w[c * 3 + k];
        }
        z = (z - rmean[c]) * rsqrtf(rvar[c] + 1e-5f) * gamma[c] + beta[c];
        g[(size_t)b * C + c] = 1.f / (1.f + expf(-z));
    }
}

// One block per (b,c): g is wave-uniform (s_load once), non-temporal stores.
__global__ void scale_kernel(const float* __restrict__ x,
                             const float* __restrict__ g,
                             float* __restrict__ out, int HW) {
    const int bc = blockIdx.x;
    const float gv = g[bc];
    const size_t base = (size_t)bc * (size_t)HW;
    const fvec4* __restrict__ x4 = (const fvec4*)(x + base);
    fvec4* __restrict__ o4 = (fvec4*)(out + base);
    const int n4 = HW >> 2;
    #pragma unroll 4
    for (int i = threadIdx.x; i < n4; i += 256) {
        fvec4 v = x4[i];
        v *= gv;
        __builtin_nontemporal_store(v, &o4[i]);
    }
}

extern "C" void kernel_launch(void* const* d_in, const int* in_sizes, int n_in,
                              void* d_out, int out_size, void* d_ws, size_t ws_size,
                              hipStream_t stream) {
    const float* x     = (const float*)d_in[0];
    const float* w     = (const float*)d_in[1];
    const float* gamma = (const float*)d_in[2];
    const float* beta  = (const float*)d_in[3];
    const float* rmean = (const float*)d_in[4];
    const float* rvar  = (const float*)d_in[5];
    float* out = (float*)d_out;

    const int C  = in_sizes[2];              // 256 (gamma)
    const int B  = 16;
    const int HW = in_sizes[0] / (B * C);    // 16384

    float* u = (float*)d_ws;                 // [B][C][3]
    float* g = u + (size_t)B * C * 3;        // [B][C]

    stats_kernel<<<B * C, 256, 0, stream>>>(x, u, HW);
    median_gate_kernel<<<B, 256, 0, stream>>>(u, w, gamma, beta, rmean, rvar, g, C);
    scale_kernel<<<B * C, 256, 0, stream>>>(x, g, out, HW);
}